// Round 4
// baseline (301.784 us; speedup 1.0000x reference)
//
#include <hip/hip_runtime.h>
#include <hip/hip_fp16.h>

#define T_TOK 1024
#define H_DIM 2048
#define I_DIM 1408
#define N_EXP 8
#define TOPK  2

using f16x8 = __attribute__((ext_vector_type(8))) _Float16;
using f32x4 = __attribute__((ext_vector_type(4))) float;

#define BM 64
#define BN 64
#define BK 64
#define NTHR 256

// ---------------- workspace layout (bytes) ----------------
#define WS_COUNTS      0
#define WS_BASES       256
#define WS_CURSORS     512
#define WS_TOPK_E      768                       // int[2048]
#define WS_TOPK_W      (768 + 8192)              // float[2048]
#define WS_TOK_OF_SLOT 17408                     // int[3072] (padded slots <= 2552)
#define WS_W_OF_SLOT   29696                     // float[3072]
#define WS_HACT        43008                     // f16[3072*1408] = 8650752 B
#define WS_NEEDED      (43008 + 8650752)

// ---------------- router ----------------
__global__ void k_router(const float* __restrict__ X, const float* __restrict__ GW,
                         int* __restrict__ counts, int* __restrict__ topk_e,
                         float* __restrict__ topk_w) {
    int t = (blockIdx.x * blockDim.x + threadIdx.x) >> 6;
    int lane = threadIdx.x & 63;
    if (t >= T_TOK) return;
    float acc[N_EXP];
#pragma unroll
    for (int e = 0; e < N_EXP; ++e) acc[e] = 0.f;
    const float* xrow = X + (size_t)t * H_DIM;
    for (int h = lane; h < H_DIM; h += 64) {
        float x = xrow[h];
        const float* g = GW + (size_t)h * N_EXP;
#pragma unroll
        for (int e = 0; e < N_EXP; ++e) acc[e] = fmaf(x, g[e], acc[e]);
    }
#pragma unroll
    for (int off = 32; off > 0; off >>= 1) {
#pragma unroll
        for (int e = 0; e < N_EXP; ++e) acc[e] += __shfl_xor(acc[e], off, 64);
    }
    if (lane == 0) {
        float m = acc[0];
#pragma unroll
        for (int e = 1; e < N_EXP; ++e) m = fmaxf(m, acc[e]);
        float ex[N_EXP], s = 0.f;
#pragma unroll
        for (int e = 0; e < N_EXP; ++e) { ex[e] = expf(acc[e] - m); s += ex[e]; }
        float inv = 1.f / s;
        int e1 = 0;
#pragma unroll
        for (int e = 1; e < N_EXP; ++e) if (ex[e] > ex[e1]) e1 = e;
        int e2 = (e1 == 0) ? 1 : 0;
#pragma unroll
        for (int e = 0; e < N_EXP; ++e) if (e != e1 && ex[e] > ex[e2]) e2 = e;
        topk_e[t * 2 + 0] = e1;
        topk_e[t * 2 + 1] = e2;
        topk_w[t * 2 + 0] = ex[e1] * inv;
        topk_w[t * 2 + 1] = ex[e2] * inv;
        atomicAdd(&counts[e1], 1);
        atomicAdd(&counts[e2], 1);
    }
}

// bases padded to BM so every M-block belongs to exactly one expert
__global__ void k_prefix(const int* __restrict__ counts, int* __restrict__ bases,
                         int* __restrict__ cursors) {
    if (threadIdx.x == 0) {
        int b = 0;
        for (int e = 0; e < N_EXP; ++e) {
            bases[e] = b;
            b += ((counts[e] + BM - 1) / BM) * BM;
            cursors[e] = 0;
        }
    }
}

__global__ void k_scatter(const int* __restrict__ topk_e, const float* __restrict__ topk_w,
                          const int* __restrict__ bases, int* __restrict__ cursors,
                          int* __restrict__ tok_of_slot, float* __restrict__ w_of_slot) {
    int t = blockIdx.x * blockDim.x + threadIdx.x;
    if (t >= T_TOK) return;
    for (int j = 0; j < TOPK; ++j) {
        int e = topk_e[t * 2 + j];
        int pos = atomicAdd(&cursors[e], 1);
        int slot = bases[e] + pos;
        tok_of_slot[slot] = t;
        w_of_slot[slot] = topk_w[t * 2 + j];
    }
}

// ===== shared GEMM pieces: 64x64 tile, BK=64, 256 thr (4 waves, 2x2 of 32x32),
// LDS [row][8 slots of 16B], slot ^= (row&7). 4-deep register prefetch. =====

#define G_COMPUTE(buf)                                                          \
    do {                                                                        \
        _Pragma("unroll") for (int ks = 0; ks < 2; ++ks) {                      \
            f16x8 af[2], bf[2];                                                 \
            _Pragma("unroll") for (int ii = 0; ii < 2; ++ii) {                  \
                int r = wm + ii * 16 + rsel;                                    \
                af[ii] = *(const f16x8*)&As[buf][r][((kq + 4 * ks) ^ (r & 7)) * 8]; \
            }                                                                   \
            _Pragma("unroll") for (int jj = 0; jj < 2; ++jj) {                  \
                int r = wn + jj * 16 + rsel;                                    \
                bf[jj] = *(const f16x8*)&Bs[buf][r][((kq + 4 * ks) ^ (r & 7)) * 8]; \
            }                                                                   \
            _Pragma("unroll") for (int ii = 0; ii < 2; ++ii)                    \
                _Pragma("unroll") for (int jj = 0; jj < 2; ++jj)                \
                    acc[ii][jj] = __builtin_amdgcn_mfma_f32_16x16x32_f16(af[ii], bf[jj], acc[ii][jj], 0, 0, 0); \
        }                                                                       \
    } while (0)

// ---------------- GEMM1: hact[slot, i] = silu(x[tok] . w1[e,:,i]) * w_slot ----------------
__global__ __launch_bounds__(NTHR, 3) void k_gemm1(
    const float* __restrict__ X, const float* __restrict__ W1,
    const int* __restrict__ counts, const int* __restrict__ bases,
    const int* __restrict__ tok_of_slot, const float* __restrict__ w_of_slot,
    _Float16* __restrict__ hact) {
    __shared__ _Float16 As[2][BM][BK];
    __shared__ _Float16 Bs[2][BN][BK];

    // XCD-aware decode: all 16 M-blocks of one (n, e) pair map to the same
    // blockIdx%8 (same XCD, dispatched consecutively) -> B-panel L2 reuse.
    const int bi = blockIdx.x;
    const int xcd = bi & 7;
    const int kk = bi >> 3;
    const int mblk = kk & 15;
    const int pair = xcd + 8 * (kk >> 4);   // 0..175
    const int e = pair & 7;
    const int n = pair >> 3;                // 0..21
    const int cnt = counts[e];
    const int m0 = mblk * BM;
    if (m0 >= cnt) return;
    const int base = bases[e];
    const int n0 = n * BN;
    const int tid = threadIdx.x;

    // A staging: thread -> (row 0..63, 16-float chunk)
    const int ar = tid >> 2;
    const int as0 = (tid & 3) * 2;          // first 16B slot
    const int r_eff = min(ar, cnt - m0 - 1);
    const float* arow = X + (size_t)tok_of_slot[base + m0 + r_eff] * H_DIM + (tid & 3) * 16;

    // B staging: thread -> (2 cols, 8 k-rows)
    const int bn2 = (tid & 31) * 2;
    const int bc = tid >> 5;                // 0..7
    const float* bcol = W1 + (size_t)e * (H_DIM * I_DIM) + (size_t)(bc * 8) * I_DIM + n0 + bn2;

    const int wid = tid >> 6, lane = tid & 63;
    const int wm = (wid >> 1) * 32, wn = (wid & 1) * 32;
    const int rsel = lane & 15, kq = lane >> 4;

    f32x4 acc[2][2] = {};

    float4 aS0[4], aS1[4], aS2[4], aS3[4];
    float2 bS0[8], bS1[8], bS2[8], bS3[8];

#define G1_LOAD(aS, bS, t)                                         \
    do {                                                           \
        const float* ap = arow + (t) * BK;                         \
        aS[0] = *(const float4*)(ap);                              \
        aS[1] = *(const float4*)(ap + 4);                          \
        aS[2] = *(const float4*)(ap + 8);                          \
        aS[3] = *(const float4*)(ap + 12);                         \
        const float* bp = bcol + (size_t)((t) * BK) * I_DIM;       \
        _Pragma("unroll") for (int j = 0; j < 8; ++j)              \
            bS[j] = *(const float2*)(bp + (size_t)j * I_DIM);      \
    } while (0)

#define G1_STORE(buf, aS, bS)                                      \
    do {                                                           \
        f16x8 p0, p1;                                              \
        _Pragma("unroll") for (int c = 0; c < 4; ++c) {            \
            p0[c] = (_Float16)aS[0][c]; p0[c + 4] = (_Float16)aS[1][c]; \
            p1[c] = (_Float16)aS[2][c]; p1[c + 4] = (_Float16)aS[3][c]; \
        }                                                          \
        *(f16x8*)&As[buf][ar][((as0) ^ (ar & 7)) * 8] = p0;        \
        *(f16x8*)&As[buf][ar][((as0 + 1) ^ (ar & 7)) * 8] = p1;    \
        f16x8 q0, q1;                                              \
        _Pragma("unroll") for (int j = 0; j < 8; ++j) {            \
            q0[j] = (_Float16)bS[j].x; q1[j] = (_Float16)bS[j].y;  \
        }                                                          \
        *(f16x8*)&Bs[buf][bn2][(bc ^ (bn2 & 7)) * 8] = q0;         \
        *(f16x8*)&Bs[buf][bn2 + 1][(bc ^ ((bn2 + 1) & 7)) * 8] = q1; \
    } while (0)

    constexpr int KT = H_DIM / BK;       // 32
    constexpr int QUADS = (KT - 1) / 4;  // 7
    constexpr int REM = (KT - 1) & 3;    // 3

    G1_LOAD(aS0, bS0, 0);
    G1_LOAD(aS1, bS1, 1);
    G1_LOAD(aS2, bS2, 2);
    G1_LOAD(aS3, bS3, 3);
    G1_STORE(0, aS0, bS0);
    __syncthreads();

    int h = 0;
    for (int q = 0; q < QUADS; ++q, h += 4) {
        if (h + 4 < KT) G1_LOAD(aS0, bS0, h + 4);
        G_COMPUTE(0); G1_STORE(1, aS1, bS1); __syncthreads();
        if (h + 5 < KT) G1_LOAD(aS1, bS1, h + 5);
        G_COMPUTE(1); G1_STORE(0, aS2, bS2); __syncthreads();
        if (h + 6 < KT) G1_LOAD(aS2, bS2, h + 6);
        G_COMPUTE(0); G1_STORE(1, aS3, bS3); __syncthreads();
        if (h + 7 < KT) G1_LOAD(aS3, bS3, h + 7);
        G_COMPUTE(1); G1_STORE(0, aS0, bS0); __syncthreads();
    }
    if constexpr (REM >= 1) { G_COMPUTE(0); G1_STORE(1, aS1, bS1); __syncthreads(); }
    if constexpr (REM >= 2) { G_COMPUTE(1); G1_STORE(0, aS2, bS2); __syncthreads(); }
    if constexpr (REM >= 3) { G_COMPUTE(0); G1_STORE(1, aS3, bS3); __syncthreads(); }
    G_COMPUTE((KT - 1) & 1);
#undef G1_LOAD
#undef G1_STORE

    const int rows = cnt - m0;
#pragma unroll
    for (int i = 0; i < 2; ++i) {
#pragma unroll
        for (int rg = 0; rg < 4; ++rg) {
            int r = wm + i * 16 + kq * 4 + rg;
            if (r < rows) {
                int slot = base + m0 + r;
                float w = w_of_slot[slot];
                _Float16* hrow = hact + (size_t)slot * I_DIM + n0;
#pragma unroll
                for (int j = 0; j < 2; ++j) {
                    float v = acc[i][j][rg];
                    hrow[wn + j * 16 + rsel] = (_Float16)(v / (1.f + expf(-v)) * w);
                }
            }
        }
    }
}

// ---------------- GEMM2: out[tok, h] += hact[slot, :] . w2[e, :, h] ----------------
__global__ __launch_bounds__(NTHR, 3) void k_gemm2(
    const _Float16* __restrict__ hact, const float* __restrict__ W2,
    const int* __restrict__ counts, const int* __restrict__ bases,
    const int* __restrict__ tok_of_slot, float* __restrict__ out) {
    __shared__ _Float16 As[2][BM][BK];
    __shared__ _Float16 Bs[2][BN][BK];

    const int bi = blockIdx.x;
    const int xcd = bi & 7;
    const int kk = bi >> 3;
    const int mblk = kk & 15;
    const int pair = xcd + 8 * (kk >> 4);   // 0..255
    const int e = pair & 7;
    const int n = pair >> 3;                // 0..31
    const int cnt = counts[e];
    const int m0 = mblk * BM;
    if (m0 >= cnt) return;
    const int base = bases[e];
    const int n0 = n * BN;
    const int tid = threadIdx.x;

    const int ar = tid >> 2;
    const int as0 = (tid & 3) * 2;
    const int r_eff = min(ar, cnt - m0 - 1);
    const _Float16* arow = hact + (size_t)(base + m0 + r_eff) * I_DIM + (tid & 3) * 16;

    const int bn2 = (tid & 31) * 2;
    const int bc = tid >> 5;
    const float* bcol = W2 + (size_t)e * (I_DIM * H_DIM) + (size_t)(bc * 8) * H_DIM + n0 + bn2;

    const int wid = tid >> 6, lane = tid & 63;
    const int wm = (wid >> 1) * 32, wn = (wid & 1) * 32;
    const int rsel = lane & 15, kq = lane >> 4;

    f32x4 acc[2][2] = {};

    f16x8 aS0[2], aS1[2], aS2[2], aS3[2];
    float2 bS0[8], bS1[8], bS2[8], bS3[8];

#define G2_LOAD(aS, bS, t)                                         \
    do {                                                           \
        const _Float16* ap = arow + (t) * BK;                      \
        aS[0] = *(const f16x8*)(ap);                               \
        aS[1] = *(const f16x8*)(ap + 8);                           \
        const float* bp = bcol + (size_t)((t) * BK) * H_DIM;       \
        _Pragma("unroll") for (int j = 0; j < 8; ++j)              \
            bS[j] = *(const float2*)(bp + (size_t)j * H_DIM);      \
    } while (0)

#define G2_STORE(buf, aS, bS)                                      \
    do {                                                           \
        *(f16x8*)&As[buf][ar][((as0) ^ (ar & 7)) * 8] = aS[0];     \
        *(f16x8*)&As[buf][ar][((as0 + 1) ^ (ar & 7)) * 8] = aS[1]; \
        f16x8 q0, q1;                                              \
        _Pragma("unroll") for (int j = 0; j < 8; ++j) {            \
            q0[j] = (_Float16)bS[j].x; q1[j] = (_Float16)bS[j].y;  \
        }                                                          \
        *(f16x8*)&Bs[buf][bn2][(bc ^ (bn2 & 7)) * 8] = q0;         \
        *(f16x8*)&Bs[buf][bn2 + 1][(bc ^ ((bn2 + 1) & 7)) * 8] = q1; \
    } while (0)

    constexpr int KT = I_DIM / BK;       // 22
    constexpr int QUADS = (KT - 1) / 4;  // 5
    constexpr int REM = (KT - 1) & 3;    // 1

    G2_LOAD(aS0, bS0, 0);
    G2_LOAD(aS1, bS1, 1);
    G2_LOAD(aS2, bS2, 2);
    G2_LOAD(aS3, bS3, 3);
    G2_STORE(0, aS0, bS0);
    __syncthreads();

    int h = 0;
    for (int q = 0; q < QUADS; ++q, h += 4) {
        if (h + 4 < KT) G2_LOAD(aS0, bS0, h + 4);
        G_COMPUTE(0); G2_STORE(1, aS1, bS1); __syncthreads();
        if (h + 5 < KT) G2_LOAD(aS1, bS1, h + 5);
        G_COMPUTE(1); G2_STORE(0, aS2, bS2); __syncthreads();
        if (h + 6 < KT) G2_LOAD(aS2, bS2, h + 6);
        G_COMPUTE(0); G2_STORE(1, aS3, bS3); __syncthreads();
        if (h + 7 < KT) G2_LOAD(aS3, bS3, h + 7);
        G_COMPUTE(1); G2_STORE(0, aS0, bS0); __syncthreads();
    }
    if constexpr (REM >= 1) { G_COMPUTE(0); G2_STORE(1, aS1, bS1); __syncthreads(); }
    if constexpr (REM >= 2) { G_COMPUTE(1); G2_STORE(0, aS2, bS2); __syncthreads(); }
    if constexpr (REM >= 3) { G_COMPUTE(0); G2_STORE(1, aS3, bS3); __syncthreads(); }
    G_COMPUTE((KT - 1) & 1);
#undef G2_LOAD
#undef G2_STORE

    const int rows = cnt - m0;
#pragma unroll
    for (int i = 0; i < 2; ++i) {
#pragma unroll
        for (int rg = 0; rg < 4; ++rg) {
            int r = wm + i * 16 + kq * 4 + rg;
            if (r < rows) {
                int slot = base + m0 + r;
                int tok = tok_of_slot[slot];
                float* orow = out + (size_t)tok * H_DIM + n0;
#pragma unroll
                for (int j = 0; j < 2; ++j)
                    atomicAdd(&orow[wn + j * 16 + rsel], acc[i][j][rg]);
            }
        }
    }
}

extern "C" void kernel_launch(void* const* d_in, const int* in_sizes, int n_in,
                              void* d_out, int out_size, void* d_ws, size_t ws_size,
                              hipStream_t stream) {
    const float* X  = (const float*)d_in[0];
    const float* GW = (const float*)d_in[1];
    const float* W1 = (const float*)d_in[2];
    const float* W2 = (const float*)d_in[3];
    float* out = (float*)d_out;
    char* ws = (char*)d_ws;
    if (ws_size < (size_t)WS_NEEDED) return;

    int*   counts      = (int*)(ws + WS_COUNTS);
    int*   bases       = (int*)(ws + WS_BASES);
    int*   cursors     = (int*)(ws + WS_CURSORS);
    int*   topk_e      = (int*)(ws + WS_TOPK_E);
    float* topk_w      = (float*)(ws + WS_TOPK_W);
    int*   tok_of_slot = (int*)(ws + WS_TOK_OF_SLOT);
    float* w_of_slot   = (float*)(ws + WS_W_OF_SLOT);
    _Float16* hact     = (_Float16*)(ws + WS_HACT);

    hipMemsetAsync(counts, 0, N_EXP * sizeof(int), stream);
    k_router<<<T_TOK / 4, 256, 0, stream>>>(X, GW, counts, topk_e, topk_w);
    k_prefix<<<1, 64, 0, stream>>>(counts, bases, cursors);
    k_scatter<<<T_TOK / 256, 256, 0, stream>>>(topk_e, topk_w, bases, cursors,
                                               tok_of_slot, w_of_slot);
    hipMemsetAsync(out, 0, (size_t)T_TOK * H_DIM * sizeof(float), stream);
    // gemm1: pairs = 22 n-blocks x 8 experts, 16 m-blocks per pair
    k_gemm1<<<8 * 22 * 16, NTHR, 0, stream>>>(
        X, W1, counts, bases, tok_of_slot, w_of_slot, hact);
    // gemm2: pairs = 32 n-blocks x 8 experts, 16 m-blocks per pair
    k_gemm2<<<8 * 32 * 16, NTHR, 0, stream>>>(
        hact, W2, counts, bases, tok_of_slot, out);
}

// Round 5
// 184.515 us; speedup vs baseline: 1.6356x; 1.6356x over previous
//
#include <hip/hip_runtime.h>
#include <hip/hip_fp16.h>

#define T_TOK 1024
#define H_DIM 2048
#define I_DIM 1408
#define N_EXP 8
#define TOPK  2

using f16x8 = __attribute__((ext_vector_type(8))) _Float16;
using f32x4 = __attribute__((ext_vector_type(4))) float;

#define BM 64
#define BN 64
#define BK 64
#define NTHR 256
#define MBLKS 32   // per-expert m-block capacity: 32*64 = 2048 slots (worst case)

// ---------------- workspace layout (bytes) ----------------
#define WS_COUNTS      0
#define WS_BASES       256
#define WS_CURSORS     512
#define WS_TOPK_E      768                       // int[2048]
#define WS_TOPK_W      (768 + 8192)              // float[2048]
#define WS_TOK_OF_SLOT 17408                     // int[3072] (padded slots <= 2552)
#define WS_W_OF_SLOT   29696                     // float[3072]
#define WS_HACT        43008                     // f16[3072*1408] = 8650752 B
#define WS_NEEDED      (43008 + 8650752)

// ---------------- router ----------------
__global__ void k_router(const float* __restrict__ X, const float* __restrict__ GW,
                         int* __restrict__ counts, int* __restrict__ topk_e,
                         float* __restrict__ topk_w) {
    int t = (blockIdx.x * blockDim.x + threadIdx.x) >> 6;
    int lane = threadIdx.x & 63;
    if (t >= T_TOK) return;
    float acc[N_EXP];
#pragma unroll
    for (int e = 0; e < N_EXP; ++e) acc[e] = 0.f;
    const float* xrow = X + (size_t)t * H_DIM;
    for (int h = lane; h < H_DIM; h += 64) {
        float x = xrow[h];
        const float* g = GW + (size_t)h * N_EXP;
#pragma unroll
        for (int e = 0; e < N_EXP; ++e) acc[e] = fmaf(x, g[e], acc[e]);
    }
#pragma unroll
    for (int off = 32; off > 0; off >>= 1) {
#pragma unroll
        for (int e = 0; e < N_EXP; ++e) acc[e] += __shfl_xor(acc[e], off, 64);
    }
    if (lane == 0) {
        float m = acc[0];
#pragma unroll
        for (int e = 1; e < N_EXP; ++e) m = fmaxf(m, acc[e]);
        float ex[N_EXP], s = 0.f;
#pragma unroll
        for (int e = 0; e < N_EXP; ++e) { ex[e] = expf(acc[e] - m); s += ex[e]; }
        float inv = 1.f / s;
        int e1 = 0;
#pragma unroll
        for (int e = 1; e < N_EXP; ++e) if (ex[e] > ex[e1]) e1 = e;
        int e2 = (e1 == 0) ? 1 : 0;
#pragma unroll
        for (int e = 0; e < N_EXP; ++e) if (e != e1 && ex[e] > ex[e2]) e2 = e;
        topk_e[t * 2 + 0] = e1;
        topk_e[t * 2 + 1] = e2;
        topk_w[t * 2 + 0] = ex[e1] * inv;
        topk_w[t * 2 + 1] = ex[e2] * inv;
        atomicAdd(&counts[e1], 1);
        atomicAdd(&counts[e2], 1);
    }
}

// bases padded to BM so every M-block belongs to exactly one expert
__global__ void k_prefix(const int* __restrict__ counts, int* __restrict__ bases,
                         int* __restrict__ cursors) {
    if (threadIdx.x == 0) {
        int b = 0;
        for (int e = 0; e < N_EXP; ++e) {
            bases[e] = b;
            b += ((counts[e] + BM - 1) / BM) * BM;
            cursors[e] = 0;
        }
    }
}

__global__ void k_scatter(const int* __restrict__ topk_e, const float* __restrict__ topk_w,
                          const int* __restrict__ bases, int* __restrict__ cursors,
                          int* __restrict__ tok_of_slot, float* __restrict__ w_of_slot) {
    int t = blockIdx.x * blockDim.x + threadIdx.x;
    if (t >= T_TOK) return;
    for (int j = 0; j < TOPK; ++j) {
        int e = topk_e[t * 2 + j];
        int pos = atomicAdd(&cursors[e], 1);
        int slot = bases[e] + pos;
        tok_of_slot[slot] = t;
        w_of_slot[slot] = topk_w[t * 2 + j];
    }
}

// ===== GEMM common: 64x64 tile, BK=64, 256 thr (4 waves, 2x2 of 32x32),
// LDS [row][8 slots of 16B], slot ^= (row&7). 2-deep register prefetch. =====

#define G_COMPUTE(buf)                                                          \
    do {                                                                        \
        _Pragma("unroll") for (int ks = 0; ks < 2; ++ks) {                      \
            f16x8 af[2], bf[2];                                                 \
            _Pragma("unroll") for (int ii = 0; ii < 2; ++ii) {                  \
                int r = wm + ii * 16 + rsel;                                    \
                af[ii] = *(const f16x8*)&As[buf][r][((kq + 4 * ks) ^ (r & 7)) * 8]; \
            }                                                                   \
            _Pragma("unroll") for (int jj = 0; jj < 2; ++jj) {                  \
                int r = wn + jj * 16 + rsel;                                    \
                bf[jj] = *(const f16x8*)&Bs[buf][r][((kq + 4 * ks) ^ (r & 7)) * 8]; \
            }                                                                   \
            _Pragma("unroll") for (int ii = 0; ii < 2; ++ii)                    \
                _Pragma("unroll") for (int jj = 0; jj < 2; ++jj)                \
                    acc[ii][jj] = __builtin_amdgcn_mfma_f32_16x16x32_f16(af[ii], bf[jj], acc[ii][jj], 0, 0, 0); \
        }                                                                       \
    } while (0)

// XCD-aware flat decode: all MBLKS m-blocks of one (n,e) pair land on the same
// blockIdx%8 (same XCD, adjacent dispatch) -> B-panel (512KB) L2 reuse.
#define G_DECODE(NB)                                \
    const int bi = blockIdx.x;                      \
    const int xcd = bi & 7;                         \
    const int kk = bi >> 3;                         \
    const int mblk = kk & (MBLKS - 1);              \
    const int P = xcd + 8 * (kk >> 5);              \
    const int e = P / (NB);                         \
    const int n = P % (NB);

// ---------------- GEMM1: hact[slot, i] = silu(x[tok] . w1[e,:,i]) * w_slot ----------------
__global__ __launch_bounds__(NTHR, 3) void k_gemm1(
    const float* __restrict__ X, const float* __restrict__ W1,
    const int* __restrict__ counts, const int* __restrict__ bases,
    const int* __restrict__ tok_of_slot, const float* __restrict__ w_of_slot,
    _Float16* __restrict__ hact) {
    __shared__ _Float16 As[2][BM][BK];
    __shared__ _Float16 Bs[2][BN][BK];

    G_DECODE(I_DIM / BN)   // 22 n-blocks
    const int cnt = counts[e];
    const int m0 = mblk * BM;
    if (m0 >= cnt) return;
    const int base = bases[e];
    const int n0 = n * BN;
    const int tid = threadIdx.x;

    // A staging: thread -> (row 0..63, 16 floats). Wave: rows 0..15 x 4 chunks -> balanced.
    const int ar = tid >> 2;
    const int as0 = (tid & 3) * 2;          // first 16B logical slot
    const int r_eff = min(ar, cnt - m0 - 1);
    const float* arow = X + (size_t)tok_of_slot[base + m0 + r_eff] * H_DIM + (tid & 3) * 16;

    // B staging: thread -> (1 col, 16 k-rows = 2 slot-groups). Wave: 64 distinct cols -> balanced.
    const int bn = tid & 63;
    const int bc2 = (tid >> 6) * 2;         // first logical slot (0,2,4,6)
    const float* bcol = W1 + (size_t)e * (H_DIM * I_DIM) + (size_t)(bc2 * 8) * I_DIM + n0 + bn;

    const int wid = tid >> 6, lane = tid & 63;
    const int wm = (wid >> 1) * 32, wn = (wid & 1) * 32;
    const int rsel = lane & 15, kq = lane >> 4;

    f32x4 acc[2][2] = {};

    float4 aS0[4], aS1[4];
    float  bS0[16], bS1[16];

#define G1_LOAD(aS, bS, k0)                                        \
    do {                                                           \
        const float* ap = arow + (k0);                             \
        aS[0] = *(const float4*)(ap);                              \
        aS[1] = *(const float4*)(ap + 4);                          \
        aS[2] = *(const float4*)(ap + 8);                          \
        aS[3] = *(const float4*)(ap + 12);                         \
        const float* bp = bcol + (size_t)(k0) * I_DIM;             \
        _Pragma("unroll") for (int j = 0; j < 16; ++j)             \
            bS[j] = bp[(size_t)j * I_DIM];                         \
    } while (0)

#define G1_STORE(buf, aS, bS)                                      \
    do {                                                           \
        f16x8 p0, p1;                                              \
        _Pragma("unroll") for (int c = 0; c < 4; ++c) {            \
            p0[c] = (_Float16)aS[0][c]; p0[c + 4] = (_Float16)aS[1][c]; \
            p1[c] = (_Float16)aS[2][c]; p1[c + 4] = (_Float16)aS[3][c]; \
        }                                                          \
        *(f16x8*)&As[buf][ar][((as0) ^ (ar & 7)) * 8] = p0;        \
        *(f16x8*)&As[buf][ar][((as0 + 1) ^ (ar & 7)) * 8] = p1;    \
        f16x8 q0, q1;                                              \
        _Pragma("unroll") for (int j = 0; j < 8; ++j) {            \
            q0[j] = (_Float16)bS[j]; q1[j] = (_Float16)bS[j + 8];  \
        }                                                          \
        *(f16x8*)&Bs[buf][bn][((bc2) ^ (bn & 7)) * 8] = q0;        \
        *(f16x8*)&Bs[buf][bn][((bc2 + 1) ^ (bn & 7)) * 8] = q1;    \
    } while (0)

    constexpr int KT = H_DIM / BK;   // 32, even
    G1_LOAD(aS0, bS0, 0);
    G1_STORE(0, aS0, bS0);
    G1_LOAD(aS0, bS0, BK);           // set0 holds tile 1
    __syncthreads();
    for (int kt = 0; kt < KT; kt += 2) {
        if (kt + 2 < KT) G1_LOAD(aS1, bS1, (kt + 2) * BK);
        G_COMPUTE(0);
        if (kt + 1 < KT) G1_STORE(1, aS0, bS0);
        __syncthreads();
        if (kt + 3 < KT) G1_LOAD(aS0, bS0, (kt + 3) * BK);
        if (kt + 1 < KT) {
            G_COMPUTE(1);
            if (kt + 2 < KT) G1_STORE(0, aS1, bS1);
            __syncthreads();
        }
    }
#undef G1_LOAD
#undef G1_STORE

    const int rows = cnt - m0;
#pragma unroll
    for (int i = 0; i < 2; ++i) {
#pragma unroll
        for (int rg = 0; rg < 4; ++rg) {
            int r = wm + i * 16 + kq * 4 + rg;
            if (r < rows) {
                int slot = base + m0 + r;
                float w = w_of_slot[slot];
                _Float16* hrow = hact + (size_t)slot * I_DIM + n0;
#pragma unroll
                for (int j = 0; j < 2; ++j) {
                    float v = acc[i][j][rg];
                    hrow[wn + j * 16 + rsel] = (_Float16)(v / (1.f + expf(-v)) * w);
                }
            }
        }
    }
}

// ---------------- GEMM2: out[tok, h] += hact[slot, :] . w2[e, :, h] ----------------
__global__ __launch_bounds__(NTHR, 3) void k_gemm2(
    const _Float16* __restrict__ hact, const float* __restrict__ W2,
    const int* __restrict__ counts, const int* __restrict__ bases,
    const int* __restrict__ tok_of_slot, float* __restrict__ out) {
    __shared__ _Float16 As[2][BM][BK];
    __shared__ _Float16 Bs[2][BN][BK];

    G_DECODE(H_DIM / BN)   // 32 n-blocks
    const int cnt = counts[e];
    const int m0 = mblk * BM;
    if (m0 >= cnt) return;
    const int base = bases[e];
    const int n0 = n * BN;
    const int tid = threadIdx.x;

    const int ar = tid >> 2;
    const int as0 = (tid & 3) * 2;
    const int r_eff = min(ar, cnt - m0 - 1);
    const _Float16* arow = hact + (size_t)(base + m0 + r_eff) * I_DIM + (tid & 3) * 16;

    const int bn = tid & 63;
    const int bc2 = (tid >> 6) * 2;
    const float* bcol = W2 + (size_t)e * (I_DIM * H_DIM) + (size_t)(bc2 * 8) * H_DIM + n0 + bn;

    const int wid = tid >> 6, lane = tid & 63;
    const int wm = (wid >> 1) * 32, wn = (wid & 1) * 32;
    const int rsel = lane & 15, kq = lane >> 4;

    f32x4 acc[2][2] = {};

    f16x8 aS0[2], aS1[2];
    float bS0[16], bS1[16];

#define G2_LOAD(aS, bS, k0)                                        \
    do {                                                           \
        const _Float16* ap = arow + (k0);                          \
        aS[0] = *(const f16x8*)(ap);                               \
        aS[1] = *(const f16x8*)(ap + 8);                           \
        const float* bp = bcol + (size_t)(k0) * H_DIM;             \
        _Pragma("unroll") for (int j = 0; j < 16; ++j)             \
            bS[j] = bp[(size_t)j * H_DIM];                         \
    } while (0)

#define G2_STORE(buf, aS, bS)                                      \
    do {                                                           \
        *(f16x8*)&As[buf][ar][((as0) ^ (ar & 7)) * 8] = aS[0];     \
        *(f16x8*)&As[buf][ar][((as0 + 1) ^ (ar & 7)) * 8] = aS[1]; \
        f16x8 q0, q1;                                              \
        _Pragma("unroll") for (int j = 0; j < 8; ++j) {            \
            q0[j] = (_Float16)bS[j]; q1[j] = (_Float16)bS[j + 8];  \
        }                                                          \
        *(f16x8*)&Bs[buf][bn][((bc2) ^ (bn & 7)) * 8] = q0;        \
        *(f16x8*)&Bs[buf][bn][((bc2 + 1) ^ (bn & 7)) * 8] = q1;    \
    } while (0)

    constexpr int KT = I_DIM / BK;   // 22, even
    G2_LOAD(aS0, bS0, 0);
    G2_STORE(0, aS0, bS0);
    G2_LOAD(aS0, bS0, BK);
    __syncthreads();
    for (int kt = 0; kt < KT; kt += 2) {
        if (kt + 2 < KT) G2_LOAD(aS1, bS1, (kt + 2) * BK);
        G_COMPUTE(0);
        if (kt + 1 < KT) G2_STORE(1, aS0, bS0);
        __syncthreads();
        if (kt + 3 < KT) G2_LOAD(aS0, bS0, (kt + 3) * BK);
        if (kt + 1 < KT) {
            G_COMPUTE(1);
            if (kt + 2 < KT) G2_STORE(0, aS1, bS1);
            __syncthreads();
        }
    }
#undef G2_LOAD
#undef G2_STORE

    const int rows = cnt - m0;
#pragma unroll
    for (int i = 0; i < 2; ++i) {
#pragma unroll
        for (int rg = 0; rg < 4; ++rg) {
            int r = wm + i * 16 + kq * 4 + rg;
            if (r < rows) {
                int slot = base + m0 + r;
                int tok = tok_of_slot[slot];
                float* orow = out + (size_t)tok * H_DIM + n0;
#pragma unroll
                for (int j = 0; j < 2; ++j)
                    atomicAdd(&orow[wn + j * 16 + rsel], acc[i][j][rg]);
            }
        }
    }
}

extern "C" void kernel_launch(void* const* d_in, const int* in_sizes, int n_in,
                              void* d_out, int out_size, void* d_ws, size_t ws_size,
                              hipStream_t stream) {
    const float* X  = (const float*)d_in[0];
    const float* GW = (const float*)d_in[1];
    const float* W1 = (const float*)d_in[2];
    const float* W2 = (const float*)d_in[3];
    float* out = (float*)d_out;
    char* ws = (char*)d_ws;
    if (ws_size < (size_t)WS_NEEDED) return;

    int*   counts      = (int*)(ws + WS_COUNTS);
    int*   bases       = (int*)(ws + WS_BASES);
    int*   cursors     = (int*)(ws + WS_CURSORS);
    int*   topk_e      = (int*)(ws + WS_TOPK_E);
    float* topk_w      = (float*)(ws + WS_TOPK_W);
    int*   tok_of_slot = (int*)(ws + WS_TOK_OF_SLOT);
    float* w_of_slot   = (float*)(ws + WS_W_OF_SLOT);
    _Float16* hact     = (_Float16*)(ws + WS_HACT);

    hipMemsetAsync(counts, 0, N_EXP * sizeof(int), stream);
    k_router<<<T_TOK / 4, 256, 0, stream>>>(X, GW, counts, topk_e, topk_w);
    k_prefix<<<1, 64, 0, stream>>>(counts, bases, cursors);
    k_scatter<<<T_TOK / 256, 256, 0, stream>>>(topk_e, topk_w, bases, cursors,
                                               tok_of_slot, w_of_slot);
    hipMemsetAsync(out, 0, (size_t)T_TOK * H_DIM * sizeof(float), stream);
    // gemm1: 22 n-blocks x 8 experts, MBLKS m-blocks per pair (XCD-decoded flat grid)
    k_gemm1<<<8 * MBLKS * 22, NTHR, 0, stream>>>(
        X, W1, counts, bases, tok_of_slot, w_of_slot, hact);
    // gemm2: 32 n-blocks x 8 experts
    k_gemm2<<<8 * MBLKS * 32, NTHR, 0, stream>>>(
        hact, W2, counts, bases, tok_of_slot, out);
}